// Round 8
// baseline (3221.111 us; speedup 1.0000x reference)
//
#include <hip/hip_runtime.h>

#define Bsz 256
#define Tt  512
#define Hh  128

// ws layout (floats):
//   Wt_ih [3][128][512]      k-major plain input weights (zero-filled k>=Kin)
//   Wt_hh [3][128][512]      k-major plain recurrent weights
//   bias  [3][512]           bih + bhh
//   hbuf  u64[4][3][256][128] 4-deep hidden states, (seq<<32)|bits(h)  (sc1 path)
//   flags [3][16][4] x 32    staging-progress flags (anti-dep only), 128B apart
#define OFF_WTHH 196608            // 3*128*512
#define OFF_BIAS 393216            // 2*196608
#define OFF_HBUF 394752            // + 3*512   (u64 array = 786432 floats)
#define OFF_FLAG 1181184           // + 786432
#define FLAG_N   6144              // 192 flags * 32 ints (128B stride)
// total used: 1187328 floats = 4.75 MB

// swizzled A-tile column: k -> (k>>3)*12 + (k&7); 8-float k-groups at 48 B stride
// -> 16 wave-distinct addrs, 2-way max bank aliasing (free), 16B-aligned b128 reads.
#define SKG(k) ((((k) >> 3) * 12) + ((k) & 7))

typedef unsigned long long u64;
typedef unsigned int u32;
typedef float f32x4 __attribute__((ext_vector_type(4)));

// ---- MALL-coherent (sc0 sc1 per-access) relaxed agent-scope atomics ----
__device__ __forceinline__ void st_h_agent(u64* p, float v, u32 seq) {
    u64 u = ((u64)seq << 32) | (u64)__float_as_uint(v);
    __hip_atomic_store(p, u, __ATOMIC_RELAXED, __HIP_MEMORY_SCOPE_AGENT);
}
__device__ __forceinline__ u64 ld_u64_agent(const u64* p) {
    return __hip_atomic_load(p, __ATOMIC_RELAXED, __HIP_MEMORY_SCOPE_AGENT);
}

// stage 4 consecutive (val,seq) pairs; spin until all carry seq==exp.
// The data IS the ready-signal: no flag round trip on the critical cycle.
__device__ __forceinline__ float4 stage4(const u64* __restrict__ src, u32 exp) {
    u64 a, b, c, d;
    for (;;) {
        a = ld_u64_agent(src + 0);
        b = ld_u64_agent(src + 1);
        c = ld_u64_agent(src + 2);
        d = ld_u64_agent(src + 3);
        if ((u32)(a >> 32) == exp && (u32)(b >> 32) == exp &&
            (u32)(c >> 32) == exp && (u32)(d >> 32) == exp) break;
    }
    return make_float4(__uint_as_float((u32)a), __uint_as_float((u32)b),
                       __uint_as_float((u32)c), __uint_as_float((u32)d));
}

// VALU-pipe partial-row reduction: lane 15 of each 16-lane DPP row ends with the
// sum of lanes 0..15. bound_ctrl=1 -> 0-fill.
template<int N>
__device__ __forceinline__ float row_shr_add(float v) {
    int s = __builtin_amdgcn_update_dpp(0, __float_as_int(v), 0x110 + N, 0xF, 0xF, true);
    return v + __int_as_float(s);
}
__device__ __forceinline__ f32x4 red16(f32x4 s) {
    s.x = row_shr_add<1>(s.x); s.x = row_shr_add<2>(s.x); s.x = row_shr_add<4>(s.x); s.x = row_shr_add<8>(s.x);
    s.y = row_shr_add<1>(s.y); s.y = row_shr_add<2>(s.y); s.y = row_shr_add<4>(s.y); s.y = row_shr_add<8>(s.y);
    s.z = row_shr_add<1>(s.z); s.z = row_shr_add<2>(s.z); s.z = row_shr_add<4>(s.z); s.z = row_shr_add<8>(s.z);
    s.w = row_shr_add<1>(s.w); s.w = row_shr_add<2>(s.w); s.w = row_shr_add<4>(s.w); s.w = row_shr_add<8>(s.w);
    return s;
}

#define FMA4(S, A, W) { S.x = fmaf(A, W.x, S.x); S.y = fmaf(A, W.y, S.y); \
                        S.z = fmaf(A, W.z, S.z); S.w = fmaf(A, W.w, S.w); }

__global__ void prep_kernel(const float* Wih0, const float* Whh0, const float* bih0, const float* bhh0,
                            const float* Wih1, const float* Whh1, const float* bih1, const float* bhh1,
                            const float* Wih2, const float* Whh2, const float* bih2, const float* bhh2,
                            float* ws)
{
    int gid = blockIdx.x * blockDim.x + threadIdx.x;   // 24*256 = 6144 threads
    if (gid < FLAG_N) ((int*)(ws + OFF_FLAG))[gid] = -1;      // anti-dep flags
    u64* hb = (u64*)(ws + OFF_HBUF);                          // seq init: never matches
    for (int i = gid; i < 4 * 3 * 256 * 128; i += 6144) hb[i] = 0xFFFFFFFF00000000ull;
    if (gid >= 3 * 512) return;
    int l = gid >> 9, gc = gid & 511;
    const float* Wih = (l == 0) ? Wih0 : (l == 1) ? Wih1 : Wih2;
    const float* Whh = (l == 0) ? Whh0 : (l == 1) ? Whh1 : Whh2;
    const float* bih = (l == 0) ? bih0 : (l == 1) ? bih1 : bih2;
    const float* bhh = (l == 0) ? bhh0 : (l == 1) ? bhh1 : bhh2;
    int Kin = (l == 0) ? 8 : 128;
    float* Wt_ih = ws + (size_t)l * 128 * 512;
    float* Wt_hh = ws + OFF_WTHH + (size_t)l * 128 * 512;
    float* bias  = ws + OFF_BIAS + l * 512;
    for (int k = 0; k < 128; k++) Wt_ih[k * 512 + gc] = (k < Kin) ? Wih[gc * Kin + k] : 0.f;
    for (int k = 0; k < 128; k++) Wt_hh[k * 512 + gc] = Whh[gc * 128 + k];
    bias[gc] = bih[gc] + bhh[gc];
}

// Persistent kernel, 192 blocks x 512 threads (8 waves -> 2 waves/SIMD).
// block = (layer, rtile, hctile); software wavefront t = s - layer.
// Readiness travels IN the h data (seq-tagged u64); flags only guard the depth-4
// buffer anti-dependence (target s-3, checked overlapped at slot start).
// vs r7: weight registers PINNED via empty asm (r7's VGPR_Count=88 proved the
// compiler was re-streaming all 32 weight quads from L2 every slot -- the hidden
// ~2 us/slot). 136 pinned quads + working set ~ 220 VGPR, still 2 waves/SIMD.
__global__ __launch_bounds__(512, 2) void lstm_kernel(const float* __restrict__ x,
                                                      float* __restrict__ ws)
{
    const float* __restrict__ bias = ws + OFF_BIAS;
    u64* __restrict__ hbuf = (u64*)(ws + OFF_HBUF);
    int* __restrict__ fl = (int*)(ws + OFF_FLAG);

    const int layer = blockIdx.x >> 6;
    const int tile  = blockIdx.x & 63;
    const int rt  = tile & 15;
    const int hct = tile >> 4;
    const int r0  = rt << 4;            // batch rows [r0, r0+16)
    const int hc0 = hct << 5;           // hidden cols [hc0, hc0+32)
    const int tid = threadIdx.x;

    __shared__ float sAin[16][192];
    __shared__ float sArec[16][192];
    __shared__ float sG[16][132];

    // zero-fill sAin (layer0 reads k>=8 against zero weights; must not be garbage)
    for (int i = tid; i < 16 * 192; i += 512) ((float*)sAin)[i] = 0.f;

    // ---- anti-dep pollers: consumers of my slot s-4 data must have staged s-3 ----
    // tid 0..3: own-layer siblings (recurrent readers); tid 4..7: downstream layer.
    int* adflag = nullptr;
    if (tid < 4)                    adflag = fl + ((layer * 16 + rt) * 4 + tid) * 32;
    else if (tid < 8 && layer < 2)  adflag = fl + (((layer + 1) * 16 + rt) * 4 + (tid - 4)) * 32;
    int* myflag = fl + ((layer * 16 + rt) * 4 + hct) * 32;

    // ---- thread tile ----
    const int kg = tid & 15;               // k-group (DPP-row lane 0..15)
    const int rg = (tid >> 4) & 1;         // row half: rows rg*8 .. rg*8+7
    const int cg = tid >> 5;               // col-group 0..15
    const int cbase = cg << 3;             // block-local col 0..120 (8 cols, same gate)
    const int gcb = ((cbase >> 5) << 7) + hc0 + (cbase & 31);   // global gate col
    const int ka = kg * 12;                // swizzled A base for this k-slice

    // ---- load weights into registers (once): 32 float4 = 128 VGPR ----
    const float* Wl_ih = ws + (size_t)layer * 65536;
    const float* Wl_hh = ws + OFF_WTHH + (size_t)layer * 65536;
    f32x4 wihA[8], wihB[8], whhA[8], whhB[8];
#pragma unroll
    for (int kk = 0; kk < 8; kk++) {
        int k = kg * 8 + kk;
        wihA[kk] = *(const f32x4*)&Wl_ih[(size_t)k * 512 + gcb];
        wihB[kk] = *(const f32x4*)&Wl_ih[(size_t)k * 512 + gcb + 4];
        whhA[kk] = *(const f32x4*)&Wl_hh[(size_t)k * 512 + gcb];
        whhB[kk] = *(const f32x4*)&Wl_hh[(size_t)k * 512 + gcb + 4];
    }
    f32x4 bias4a = *(const f32x4*)&bias[layer * 512 + gcb];
    f32x4 bias4b = *(const f32x4*)&bias[layer * 512 + gcb + 4];
    if (kg != 15) {   // bias added exactly once per col (at the reduction root lane)
        bias4a = (f32x4){0.f, 0.f, 0.f, 0.f};
        bias4b = (f32x4){0.f, 0.f, 0.f, 0.f};
    }
    // ---- PIN weights+bias in VGPRs: the empty asm's outputs become the source
    // of truth, so the compiler cannot re-load them from L2 inside the t-loop
    // (r7 disasm-by-proxy: VGPR_Count 88 < 128-reg weight footprint).
#pragma unroll
    for (int kk = 0; kk < 8; kk++) {
        asm volatile("" : "+v"(wihA[kk]), "+v"(wihB[kk]), "+v"(whhA[kk]), "+v"(whhB[kk]));
    }
    asm volatile("" : "+v"(bias4a), "+v"(bias4b));

    // staging coords: 32 threads/row x 4 floats
    const int sr = tid >> 5;               // 0..15
    const int sk = (tid & 31) << 2;        // 0,4,...,124
    const int skc = SKG(sk);

    // cell-update coords: 1 cell/thread
    const int ur = tid >> 5, uc = tid & 31;
    float creg = 0.f;

    __syncthreads();   // sAin zero-fill visible

    for (int t = 0; t < Tt; ++t) {
        const int s = t + layer;
        const int prev = (s - 1) & 3, cur = s & 3;   // depth-4 buffering
        const u32 expseq = (u32)(s - 1);

        // ---- anti-dep (depth-4 slack: target s-3; flags init -1 auto-pass early) ----
        if (adflag != nullptr) {
            const int target = s - 3;
            while (__hip_atomic_load(adflag, __ATOMIC_RELAXED, __HIP_MEMORY_SCOPE_AGENT) < target)
                ;
        }

        // ---- stage A tiles into LDS; the seq tags ARE the ready-signal ----
        if (layer == 0) {
            if (tid < 128) {
                int r = tid >> 3, i = tid & 7;
                sAin[r][i] = x[((size_t)(r0 + r) * Tt + t) * 8 + i];
            }
        } else {
            const u64* src = hbuf + ((size_t)prev * 3 + (layer - 1)) * Bsz * Hh
                           + (size_t)(r0 + sr) * Hh + sk;
            *(float4*)&sAin[sr][skc] = stage4(src, expseq);
        }
        if (t > 0) {
            const u64* src = hbuf + ((size_t)prev * 3 + layer) * Bsz * Hh
                           + (size_t)(r0 + sr) * Hh + sk;
            *(float4*)&sArec[sr][skc] = stage4(src, expseq);
        }
        __syncthreads();   // barA: staging done (also orders anti-dep poll before stores)

        // publish "staged slot s" (earliest legal point: my reads of s-1 are complete)
        if (tid == 0)
            __hip_atomic_store(myflag, s, __ATOMIC_RELAXED, __HIP_MEMORY_SCOPE_AGENT);

        // ---- GEMM: register weights x LDS A-slices (8 rows x 8 cols / thread) ----
#pragma unroll
        for (int j = 0; j < 8; j++) {
            const int r = rg * 8 + j;
            f32x4 acc0 = bias4a, acc1 = bias4b;
            {
                float4 a0 = *(const float4*)&sAin[r][ka];
                float4 a1 = *(const float4*)&sAin[r][ka + 4];
                FMA4(acc0, a0.x, wihA[0]); FMA4(acc1, a0.x, wihB[0]);
                FMA4(acc0, a0.y, wihA[1]); FMA4(acc1, a0.y, wihB[1]);
                FMA4(acc0, a0.z, wihA[2]); FMA4(acc1, a0.z, wihB[2]);
                FMA4(acc0, a0.w, wihA[3]); FMA4(acc1, a0.w, wihB[3]);
                FMA4(acc0, a1.x, wihA[4]); FMA4(acc1, a1.x, wihB[4]);
                FMA4(acc0, a1.y, wihA[5]); FMA4(acc1, a1.y, wihB[5]);
                FMA4(acc0, a1.z, wihA[6]); FMA4(acc1, a1.z, wihB[6]);
                FMA4(acc0, a1.w, wihA[7]); FMA4(acc1, a1.w, wihB[7]);
            }
            if (t > 0) {
                float4 b0 = *(const float4*)&sArec[r][ka];
                float4 b1 = *(const float4*)&sArec[r][ka + 4];
                FMA4(acc0, b0.x, whhA[0]); FMA4(acc1, b0.x, whhB[0]);
                FMA4(acc0, b0.y, whhA[1]); FMA4(acc1, b0.y, whhB[1]);
                FMA4(acc0, b0.z, whhA[2]); FMA4(acc1, b0.z, whhB[2]);
                FMA4(acc0, b0.w, whhA[3]); FMA4(acc1, b0.w, whhB[3]);
                FMA4(acc0, b1.x, whhA[4]); FMA4(acc1, b1.x, whhB[4]);
                FMA4(acc0, b1.y, whhA[5]); FMA4(acc1, b1.y, whhB[5]);
                FMA4(acc0, b1.z, whhA[6]); FMA4(acc1, b1.z, whhB[6]);
                FMA4(acc0, b1.w, whhA[7]); FMA4(acc1, b1.w, whhB[7]);
            }
            acc0 = red16(acc0);            // lane kg==15: full sum + bias
            acc1 = red16(acc1);
            if (kg == 15) {
                *(f32x4*)&sG[r][cbase]     = acc0;
                *(f32x4*)&sG[r][cbase + 4] = acc1;
            }
        }
        __syncthreads();   // barB: sG visible

        // ---- LSTM cell update: 1 cell/thread; store (h,seq) -- the signal itself ----
        {
            float gi = sG[ur][uc],      gf = sG[ur][32 + uc];
            float gg = sG[ur][64 + uc], go = sG[ur][96 + uc];
            float si = 1.f / (1.f + __expf(-gi));
            float sf = 1.f / (1.f + __expf(-gf));
            float so = 1.f / (1.f + __expf(-go));
            creg = sf * creg + si * tanhf(gg);
            u64* dst = hbuf + ((size_t)cur * 3 + layer) * Bsz * Hh
                     + (size_t)(r0 + ur) * Hh + hc0 + uc;
            st_h_agent(dst, so * tanhf(creg), (u32)s);
        }
        // no barrier: next-slot staging conflicts only with GEMM reads (ended at barB)
        // and cell's sG reads (ordered before next GEMM by next barA).
    }
}

__global__ void fc_kernel(const float* __restrict__ ws, const float* __restrict__ Wfc,
                          const float* __restrict__ bfc, float* __restrict__ out)
{
    // final h of layer2 written at s=513 -> 513&3 = 1 -> hbuf[1][2]
    const u64* h2 = (const u64*)(ws + OFF_HBUF) + (size_t)(1 * 3 + 2) * Bsz * Hh;
    int b = threadIdx.x;   // 256 threads
    float a0 = bfc[0], a1 = bfc[1], a2 = bfc[2];
    for (int k = 0; k < 128; k++) {
        float h = __uint_as_float((u32)h2[b * 128 + k]);
        a0 += h * Wfc[0 * 128 + k];
        a1 += h * Wfc[1 * 128 + k];
        a2 += h * Wfc[2 * 128 + k];
    }
    out[b * 3 + 0] = a0;
    out[b * 3 + 1] = a1;
    out[b * 3 + 2] = a2;
}

extern "C" void kernel_launch(void* const* d_in, const int* in_sizes, int n_in,
                              void* d_out, int out_size, void* d_ws, size_t ws_size,
                              hipStream_t stream)
{
    const float* x = (const float*)d_in[0];
    float* ws = (float*)d_ws;

    prep_kernel<<<24, 256, 0, stream>>>(
        (const float*)d_in[1],  (const float*)d_in[2],  (const float*)d_in[3],  (const float*)d_in[4],
        (const float*)d_in[5],  (const float*)d_in[6],  (const float*)d_in[7],  (const float*)d_in[8],
        (const float*)d_in[9],  (const float*)d_in[10], (const float*)d_in[11], (const float*)d_in[12],
        ws);

    // cooperative launch solely for the co-residency guarantee (no grid.sync inside)
    void* args[2] = { (void*)&x, (void*)&ws };
    hipLaunchCooperativeKernel((void*)lstm_kernel, dim3(192), dim3(512), args, 0, stream);

    fc_kernel<<<1, 256, 0, stream>>>(ws, (const float*)d_in[13], (const float*)d_in[14], (float*)d_out);
}